// Round 4
// baseline (375.918 us; speedup 1.0000x reference)
//
#include <hip/hip_runtime.h>
#include <hip/hip_bf16.h>
#include <stdint.h>

#define B_DIM 64
#define S_DIM 512
#define K_DIM 1024   // F_IN
#define N_DIM 1024   // F_OUT
#define M_DIM (B_DIM * S_DIM)  // 32768
#define BK 32
#define KTILES (K_DIM / BK)    // 32

typedef __attribute__((ext_vector_type(8))) short short8;
typedef __attribute__((ext_vector_type(4))) float floatx4;

// ---------------------------------------------------------------------------
// Kernel 1: chunked EMA scan along S on x (fp32) fused with fp32->bf16.
// scan_S(x) @ W^T == scan_S(x @ W^T) (linearity). alpha=0.5 forgets at 0.5^k:
// 16-step warm-up restart is exact to ~1.5e-5 (vs 6.9e-2 threshold).
// S=512 in 8 chunks of 64 (warm 16): reads 160 MB (vs 192 with chunk=32).
// ---------------------------------------------------------------------------
__global__ __launch_bounds__(256) void scan_x_kernel(
    const float* __restrict__ x, __hip_bfloat16* __restrict__ xs) {
  const int t  = blockIdx.x * 256 + threadIdx.x;   // 0..131071
  const int f4 = (t & 255) << 2;                   // feature start 0..1020
  const int c  = (t >> 8) & 7;                     // S-chunk 0..7 (block-uniform)
  const int b  = t >> 11;                          // batch 0..63
  const size_t base = (size_t)b * S_DIM * K_DIM + f4;
  const int s0 = c * 64;

  float4 h = {0.f, 0.f, 0.f, 0.f};
  if (c != 0) {                                    // block-uniform branch
    #pragma unroll 8
    for (int s = s0 - 16; s < s0; ++s) {
      float4 v = *(const float4*)(x + base + (size_t)s * K_DIM);
      h.x = 0.5f * (h.x + v.x); h.y = 0.5f * (h.y + v.y);
      h.z = 0.5f * (h.z + v.z); h.w = 0.5f * (h.w + v.w);
    }
  }
  #pragma unroll 8
  for (int s = s0; s < s0 + 64; ++s) {
    float4 v = *(const float4*)(x + base + (size_t)s * K_DIM);
    h.x = 0.5f * (h.x + v.x); h.y = 0.5f * (h.y + v.y);
    h.z = 0.5f * (h.z + v.z); h.w = 0.5f * (h.w + v.w);
    __hip_bfloat16 b0 = __float2bfloat16(h.x);
    __hip_bfloat16 b1 = __float2bfloat16(h.y);
    __hip_bfloat16 b2 = __float2bfloat16(h.z);
    __hip_bfloat16 b3 = __float2bfloat16(h.w);
    union { unsigned short u[4]; uint2 v2; } pk;
    pk.u[0] = *(unsigned short*)&b0; pk.u[1] = *(unsigned short*)&b1;
    pk.u[2] = *(unsigned short*)&b2; pk.u[3] = *(unsigned short*)&b3;
    *(uint2*)(xs + base + (size_t)s * K_DIM) = pk.v2;
  }
}

// ---------------------------------------------------------------------------
// Kernel 2: W fp32 -> bf16 (tiny: 1M elements)
// ---------------------------------------------------------------------------
__global__ __launch_bounds__(256) void conv_w_kernel(
    const float* __restrict__ W, __hip_bfloat16* __restrict__ Wb) {
  int t = blockIdx.x * 256 + threadIdx.x;
  Wb[t] = __float2bfloat16(W[t]);
}

// ---------------------------------------------------------------------------
// Kernel 3: bf16 NT GEMM, 128x128 tile, BK=32, explicit LDS double-buffer
// with ONE barrier per K-step: stage(t+1) is issued right after the barrier,
// then compute(t) runs -> the vmcnt(0) drain at the next barrier waits only
// on loads that already had a full compute phase in flight. (R3 was
// serialized stage->drain->compute with ~1.5 blocks/CU resident: MfmaUtil
// 24%, HBM 21%, nothing saturated = latency-bound.)
//
// LDS layout is k-major at 16B-chunk granularity: chunk c = q*128 + row
// (global_load_lds constrains only the LDS dest to be lane-contiguous; the
// global source may scatter). Frag reads are bank-even without swizzle.
//
// MFMA operands SWAPPED: mfma(bfr, af, acc) computes the C^T tile, whose
// C/D layout (col=lane&15 -> m, row=quad*4+reg -> n) puts 4 consecutive n
// in regs 0..3 -> epilogue is 16 global_store_dwordx4 (was 64 scalar).
// ---------------------------------------------------------------------------
__global__ __launch_bounds__(256, 4) void gemm_kernel(
    const __hip_bfloat16* __restrict__ A,   // [M, K] scanned x
    const __hip_bfloat16* __restrict__ Bw,  // [N, K] W (torch Linear layout)
    float* __restrict__ out) {
  __shared__ __hip_bfloat16 lA[2][128 * BK];  // 2 x 8 KB
  __shared__ __hip_bfloat16 lB[2][128 * BK];  // 2 x 8 KB

  const int tid  = threadIdx.x;
  const int lane = tid & 63;
  const int w    = tid >> 6;        // wave 0..3
  const int wm   = (w >> 1) * 64;   // wave m offset within tile
  const int wn   = (w & 1) * 64;    // wave n offset within tile
  const int quad = lane >> 4;       // 0..3
  const int l15  = lane & 15;

  // XCD swizzle (R3-verified: FETCH 266->66 MB): blocks sharing an A-tile
  // stay on one XCD; B (2 MB) is L2-resident per XCD.
  const int bi    = blockIdx.x;     // 0..2047
  const int xcd   = bi & 7;
  const int local = bi >> 3;        // 0..255
  const int m0 = (xcd * 32 + (local >> 3)) * 128;
  const int n0 = (local & 7) * 128;

  auto stage = [&](int t, int bsel) {
    const int k0 = t * BK;
    #pragma unroll
    for (int p = 0; p < 2; ++p) {
      int c = tid + p * 256;        // 16-B chunk id 0..511
      int q = c >> 7;               // k-chunk 0..3
      int r = c & 127;              // tile row
      const __hip_bfloat16* ga = A  + (size_t)(m0 + r) * K_DIM + k0 + q * 8;
      const __hip_bfloat16* gb = Bw + (size_t)(n0 + r) * K_DIM + k0 + q * 8;
      __builtin_amdgcn_global_load_lds(
          (const __attribute__((address_space(1))) void*)ga,
          (__attribute__((address_space(3))) void*)&lA[bsel][c * 8], 16, 0, 0);
      __builtin_amdgcn_global_load_lds(
          (const __attribute__((address_space(1))) void*)gb,
          (__attribute__((address_space(3))) void*)&lB[bsel][c * 8], 16, 0, 0);
    }
  };

  floatx4 acc[4][4] = {};
  stage(0, 0);

  for (int t = 0; t < KTILES; ++t) {
    __syncthreads();                // drains stage(t) (issued last iter) +
                                    // guards buf[(t+1)&1] against live readers
    if (t + 1 < KTILES) stage(t + 1, (t + 1) & 1);

    const __hip_bfloat16* bufA = lA[t & 1];
    const __hip_bfloat16* bufB = lB[t & 1];
    // Frag: row R, k-chunk quad -> LDS chunk (quad*128 + R)
    short8 af[4], bfr[4];
    #pragma unroll
    for (int i = 0; i < 4; ++i)
      af[i]  = *(const short8*)&bufA[(quad * 128 + wm + i * 16 + l15) * 8];
    #pragma unroll
    for (int j = 0; j < 4; ++j)
      bfr[j] = *(const short8*)&bufB[(quad * 128 + wn + j * 16 + l15) * 8];
    #pragma unroll
    for (int i = 0; i < 4; ++i)
      #pragma unroll
      for (int j = 0; j < 4; ++j)
        acc[i][j] = __builtin_amdgcn_mfma_f32_16x16x32_bf16(
            bfr[j], af[i], acc[i][j], 0, 0, 0);   // SWAPPED -> C^T layout
  }

  // Epilogue: D (swapped) layout: col=lane&15 = m_local, row=quad*4+reg = n_local.
  // Regs 0..3 of acc[i][j] are n = quad*4 .. quad*4+3 -> one dwordx4 each.
  float* hid = out + B_DIM * N_DIM;  // hiddens after hk (65536 floats)
  #pragma unroll
  for (int i = 0; i < 4; ++i) {
    const int gm = m0 + wm + i * 16 + l15;
    const bool is_last = (gm & (S_DIM - 1)) == (S_DIM - 1);  // s == 511
    #pragma unroll
    for (int j = 0; j < 4; ++j) {
      const int gn = n0 + wn + j * 16 + quad * 4;
      *(floatx4*)&hid[(size_t)gm * N_DIM + gn] = acc[i][j];
      if (is_last)
        *(floatx4*)&out[(size_t)(gm >> 9) * N_DIM + gn] = acc[i][j];  // hk[b,n]
    }
  }
}

extern "C" void kernel_launch(void* const* d_in, const int* in_sizes, int n_in,
                              void* d_out, int out_size, void* d_ws, size_t ws_size,
                              hipStream_t stream) {
  const float* x = (const float*)d_in[0];   // [64, 512, 1024] fp32
  const float* W = (const float*)d_in[1];   // [1024, 1024] fp32
  float* out = (float*)d_out;               // [65536 hk][33.55M hiddens] fp32

  __hip_bfloat16* xs = (__hip_bfloat16*)d_ws;
  __hip_bfloat16* Wb = (__hip_bfloat16*)((char*)d_ws + (size_t)M_DIM * K_DIM * 2);

  scan_x_kernel<<<dim3(131072 / 256), dim3(256), 0, stream>>>(x, xs);
  conv_w_kernel<<<dim3((N_DIM * K_DIM) / 256), dim3(256), 0, stream>>>(W, Wb);
  gemm_kernel<<<dim3((M_DIM / 128) * (N_DIM / 128)), dim3(256), 0, stream>>>(xs, Wb, out);
}